// Round 1
// baseline (689.893 us; speedup 1.0000x reference)
//
#include <hip/hip_runtime.h>
#include <math.h>

#define NNODES 50000
#define NEDGES 800000
#define NLAYERS 3
#define NHEADS 2
#define NCH 64
#define FDIM 128   // == NHEADS*NCH
#define NCLS 10
#define NGRAPH 64
#define NEG_SLOPE 0.2f

// ---------------- CSR build ----------------

__global__ void k_init(int* __restrict__ cnt, float* __restrict__ gsum,
                       float* __restrict__ gcnt) {
  int i = blockIdx.x * 256 + threadIdx.x;
  if (i < NNODES) cnt[i] = 1;              // seed with the self-loop
  if (i < NGRAPH * FDIM) gsum[i] = 0.f;
  if (i < NGRAPH) gcnt[i] = 0.f;
}

__global__ void k_hist(const int* __restrict__ ei, int* __restrict__ cnt) {
  int e = blockIdx.x * 256 + threadIdx.x;
  if (e < NEDGES) atomicAdd(&cnt[ei[NEDGES + e]], 1);
}

__global__ __launch_bounds__(1024) void k_scan(int* __restrict__ cnt_cursor,
                                               int* __restrict__ row_ptr) {
  __shared__ int ps[1024];
  int t = threadIdx.x;
  const int CH = (NNODES + 1023) / 1024;   // 49
  int s0 = t * CH;
  int s1 = min(s0 + CH, NNODES);
  int sum = 0;
  for (int i = s0; i < s1; ++i) sum += cnt_cursor[i];
  ps[t] = sum;
  __syncthreads();
  for (int off = 1; off < 1024; off <<= 1) {
    int v = 0;
    if (t >= off) v = ps[t - off];
    __syncthreads();
    ps[t] += v;
    __syncthreads();
  }
  int run = (t > 0) ? ps[t - 1] : 0;
  for (int i = s0; i < s1; ++i) {
    int c = cnt_cursor[i];
    row_ptr[i] = run;
    cnt_cursor[i] = run;   // becomes the scatter cursor
    run += c;
  }
  if (t == 1023) row_ptr[NNODES] = ps[1023];
}

__global__ void k_scatter(const int* __restrict__ ei, int* __restrict__ cursor,
                          int* __restrict__ csr) {
  int t = blockIdx.x * 256 + threadIdx.x;
  if (t < NEDGES) {
    int s = ei[t];
    int d = ei[NEDGES + t];
    int pos = atomicAdd(&cursor[d], 1);
    csr[pos] = s;
  } else if (t < NEDGES + NNODES) {
    int i = t - NEDGES;           // self-loop
    int pos = atomicAdd(&cursor[i], 1);
    csr[pos] = i;
  }
}

// ---------------- per-layer kernels ----------------

// H[row,:] = X[row,:] @ Wg (128x128), fp32. 64-row tiles, K chunks of 32.
__global__ __launch_bounds__(256) void k_gemm(const float* __restrict__ X,
                                              const float* __restrict__ Wg,
                                              float* __restrict__ H) {
  __shared__ float Xs[64][33];
  __shared__ float Ws[32][128];
  int t = threadIdx.x;
  int row0 = blockIdx.x * 64;
  int col = (t & 31) * 4;
  int rbase = (t >> 5) * 8;
  float acc[8][4];
#pragma unroll
  for (int i = 0; i < 8; ++i)
#pragma unroll
    for (int j = 0; j < 4; ++j) acc[i][j] = 0.f;

  for (int k0 = 0; k0 < 128; k0 += 32) {
    {  // stage X tile (64 rows x 32 k)
      int xr = t >> 2, xk = (t & 3) * 8;
      int gr = row0 + xr;
      float4 v0 = make_float4(0.f, 0.f, 0.f, 0.f), v1 = v0;
      if (gr < NNODES) {
        const float* p = X + (size_t)gr * 128 + k0 + xk;
        v0 = *(const float4*)p;
        v1 = *(const float4*)(p + 4);
      }
      Xs[xr][xk + 0] = v0.x; Xs[xr][xk + 1] = v0.y;
      Xs[xr][xk + 2] = v0.z; Xs[xr][xk + 3] = v0.w;
      Xs[xr][xk + 4] = v1.x; Xs[xr][xk + 5] = v1.y;
      Xs[xr][xk + 6] = v1.z; Xs[xr][xk + 7] = v1.w;
    }
    {  // stage W tile (32 k x 128 cols)
      int wr = t >> 3, wc = (t & 7) * 16;
      const float* p = Wg + (size_t)(k0 + wr) * 128 + wc;
#pragma unroll
      for (int j = 0; j < 4; ++j) {
        float4 v = *(const float4*)(p + 4 * j);
        *(float4*)&Ws[wr][wc + 4 * j] = v;
      }
    }
    __syncthreads();
#pragma unroll
    for (int kk = 0; kk < 32; ++kk) {
      float4 b = *(const float4*)&Ws[kk][col];
#pragma unroll
      for (int i = 0; i < 8; ++i) {
        float a = Xs[rbase + i][kk];
        acc[i][0] += a * b.x;
        acc[i][1] += a * b.y;
        acc[i][2] += a * b.z;
        acc[i][3] += a * b.w;
      }
    }
    __syncthreads();
  }
#pragma unroll
  for (int i = 0; i < 8; ++i) {
    int r = row0 + rbase + i;
    if (r < NNODES) {
      float4 v = make_float4(acc[i][0], acc[i][1], acc[i][2], acc[i][3]);
      *(float4*)&H[(size_t)r * 128 + col] = v;
    }
  }
}

// alpha_src / alpha_dst per (node, head): one wave per pair.
__global__ __launch_bounds__(256) void k_alpha(const float* __restrict__ H,
                                               const float* __restrict__ a_s,
                                               const float* __restrict__ a_d,
                                               float* __restrict__ as_,
                                               float* __restrict__ ad_) {
  int t = threadIdx.x;
  int node = blockIdx.x * 2 + (t >> 7);
  if (node >= NNODES) return;
  int i = t & 127;  // hd*64 + c
  float hv = H[(size_t)node * 128 + i];
  float ps = hv * a_s[i];
  float pd = hv * a_d[i];
#pragma unroll
  for (int off = 32; off > 0; off >>= 1) {
    ps += __shfl_down(ps, off, 64);
    pd += __shfl_down(pd, off, 64);
  }
  if ((t & 63) == 0) {
    int hd = i >> 6;
    as_[node * 2 + hd] = ps;
    ad_[node * 2 + hd] = pd;
  }
}

// One wave per node: softmax over incoming edges + weighted aggregation.
__global__ __launch_bounds__(256) void k_aggregate(
    const float* __restrict__ H, const float* __restrict__ as_,
    const float* __restrict__ ad_, const int* __restrict__ row_ptr,
    const int* __restrict__ csr, const float* __restrict__ bias,
    float* __restrict__ Xout) {
  __shared__ float2 wb[4][64];
  __shared__ int sb[4][64];
  int wv = threadIdx.x >> 6;
  int lane = threadIdx.x & 63;
  int node = blockIdx.x * 4 + wv;
  if (node >= NNODES) return;
  int rs = row_ptr[node], re = row_ptr[node + 1];
  float2 adv = *(const float2*)&ad_[node * 2];

  // pass 1: per-head max of leaky_relu(as[src] + ad[node])
  float m0 = -INFINITY, m1 = -INFINITY;
  for (int j = rs + lane; j < re; j += 64) {
    int s = csr[j];
    float2 asv = *(const float2*)&as_[s * 2];
    float e0 = asv.x + adv.x; e0 = (e0 > 0.f) ? e0 : NEG_SLOPE * e0;
    float e1 = asv.y + adv.y; e1 = (e1 > 0.f) ? e1 : NEG_SLOPE * e1;
    m0 = fmaxf(m0, e0);
    m1 = fmaxf(m1, e1);
  }
#pragma unroll
  for (int off = 32; off > 0; off >>= 1) {
    m0 = fmaxf(m0, __shfl_xor(m0, off, 64));
    m1 = fmaxf(m1, __shfl_xor(m1, off, 64));
  }

  // pass 2: p = exp(e - m); z = sum p; acc = sum p * h[src]
  float z0 = 0.f, z1 = 0.f, acc0 = 0.f, acc1 = 0.f;
  for (int base = rs; base < re; base += 64) {
    int j = base + lane;
    float p0 = 0.f, p1 = 0.f;
    int s = 0;
    if (j < re) {
      s = csr[j];
      float2 asv = *(const float2*)&as_[s * 2];
      float e0 = asv.x + adv.x; e0 = (e0 > 0.f) ? e0 : NEG_SLOPE * e0;
      float e1 = asv.y + adv.y; e1 = (e1 > 0.f) ? e1 : NEG_SLOPE * e1;
      p0 = expf(e0 - m0);
      p1 = expf(e1 - m1);
    }
    z0 += p0;
    z1 += p1;
    wb[wv][lane] = make_float2(p0, p1);
    sb[wv][lane] = s;
    __builtin_amdgcn_wave_barrier();
    __asm__ volatile("" ::: "memory");
    int cl = min(64, re - base);
    for (int jj = 0; jj < cl; ++jj) {
      int ss = sb[wv][jj];
      float2 w = wb[wv][jj];
      const float* hp = H + (size_t)ss * 128 + lane;
      acc0 += w.x * hp[0];
      acc1 += w.y * hp[64];
    }
    __builtin_amdgcn_wave_barrier();
    __asm__ volatile("" ::: "memory");
  }
#pragma unroll
  for (int off = 32; off > 0; off >>= 1) {
    z0 += __shfl_xor(z0, off, 64);
    z1 += __shfl_xor(z1, off, 64);
  }
  float o0 = acc0 / z0 + bias[lane];
  float o1 = acc1 / z1 + bias[64 + lane];
  o0 = (o0 > 0.f) ? o0 : expm1f(o0);  // ELU
  o1 = (o1 > 0.f) ? o1 : expm1f(o1);
  Xout[(size_t)node * 128 + lane] = o0;
  Xout[(size_t)node * 128 + 64 + lane] = o1;
}

// ---------------- pooling + classifier ----------------

__global__ __launch_bounds__(128) void k_pool(const float* __restrict__ Xf,
                                              const int* __restrict__ batch,
                                              float* __restrict__ gsum) {
  int c = threadIdx.x;
  int n0 = blockIdx.x * 256;
  if (n0 >= NNODES) return;
  int n1 = min(n0 + 256, NNODES);
  int cur = batch[n0];
  float acc = 0.f;
  for (int n = n0; n < n1; ++n) {
    int g = batch[n];
    if (g != cur) {
      atomicAdd(&gsum[cur * FDIM + c], acc);
      acc = 0.f;
      cur = g;
    }
    acc += Xf[(size_t)n * 128 + c];
  }
  atomicAdd(&gsum[cur * FDIM + c], acc);
}

__global__ __launch_bounds__(256) void k_cnt(const int* __restrict__ batch,
                                             float* __restrict__ gcnt) {
  __shared__ float loc[NGRAPH];
  int t = threadIdx.x;
  if (t < NGRAPH) loc[t] = 0.f;
  __syncthreads();
  int n = blockIdx.x * 256 + t;
  if (n < NNODES) atomicAdd(&loc[batch[n]], 1.f);
  __syncthreads();
  if (t < NGRAPH && loc[t] > 0.f) atomicAdd(&gcnt[t], loc[t]);
}

__global__ __launch_bounds__(64) void k_final(const float* __restrict__ gsum,
                                              const float* __restrict__ gcnt,
                                              const float* __restrict__ lw,
                                              const float* __restrict__ lb,
                                              float* __restrict__ out) {
  int g = threadIdx.x;
  float inv = 1.f / fmaxf(gcnt[g], 1.f);
  float lg[NCLS];
#pragma unroll
  for (int k = 0; k < NCLS; ++k) lg[k] = lb[k];
  for (int c = 0; c < FDIM; ++c) {
    float pv = gsum[g * FDIM + c] * inv;
#pragma unroll
    for (int k = 0; k < NCLS; ++k) lg[k] += pv * lw[c * NCLS + k];
  }
  float mx = lg[0];
#pragma unroll
  for (int k = 1; k < NCLS; ++k) mx = fmaxf(mx, lg[k]);
  float s = 0.f;
#pragma unroll
  for (int k = 0; k < NCLS; ++k) {
    lg[k] = expf(lg[k] - mx);
    s += lg[k];
  }
  float invs = 1.f / s;
#pragma unroll
  for (int k = 0; k < NCLS; ++k) out[g * NCLS + k] = lg[k] * invs;
}

// ---------------- launch ----------------

extern "C" void kernel_launch(void* const* d_in, const int* in_sizes, int n_in,
                              void* d_out, int out_size, void* d_ws,
                              size_t ws_size, hipStream_t stream) {
  const float* x = (const float*)d_in[0];
  const int* ei = (const int*)d_in[1];
  const int* batch = (const int*)d_in[2];
  const float* W = (const float*)d_in[3];
  const float* a_s = (const float*)d_in[4];
  const float* a_d = (const float*)d_in[5];
  const float* bias = (const float*)d_in[6];
  const float* lw = (const float*)d_in[7];
  const float* lb = (const float*)d_in[8];
  float* out = (float*)d_out;

  float* ws = (float*)d_ws;
  float* h = ws;                                   // N*128
  float* xb = h + (size_t)NNODES * 128;            // N*128
  float* as_ = xb + (size_t)NNODES * 128;          // N*2
  float* ad_ = as_ + (size_t)NNODES * 2;           // N*2
  float* gsum = ad_ + (size_t)NNODES * 2;          // 64*128
  float* gcnt = gsum + NGRAPH * FDIM;              // 64
  int* row_ptr = (int*)(gcnt + NGRAPH);            // N+1
  int* cursor = row_ptr + (NNODES + 1);            // N
  int* csr = cursor + NNODES;                      // E+N

  // CSR build (graph is layer-invariant)
  k_init<<<(NNODES + 255) / 256, 256, 0, stream>>>(cursor, gsum, gcnt);
  k_hist<<<(NEDGES + 255) / 256, 256, 0, stream>>>(ei, cursor);
  k_scan<<<1, 1024, 0, stream>>>(cursor, row_ptr);
  k_scatter<<<(NEDGES + NNODES + 255) / 256, 256, 0, stream>>>(ei, cursor, csr);

  const float* xin = x;
  for (int l = 0; l < NLAYERS; ++l) {
    k_gemm<<<(NNODES + 63) / 64, 256, 0, stream>>>(xin, W + l * FDIM * FDIM, h);
    k_alpha<<<(NNODES + 1) / 2, 256, 0, stream>>>(h, a_s + l * FDIM,
                                                  a_d + l * FDIM, as_, ad_);
    k_aggregate<<<(NNODES + 3) / 4, 256, 0, stream>>>(
        h, as_, ad_, row_ptr, csr, bias + l * FDIM, xb);
    xin = xb;
  }
  k_pool<<<(NNODES + 255) / 256, 128, 0, stream>>>(xb, batch, gsum);
  k_cnt<<<(NNODES + 255) / 256, 256, 0, stream>>>(batch, gcnt);
  k_final<<<1, 64, 0, stream>>>(gsum, gcnt, lw, lb, out);
}

// Round 2
// 498.561 us; speedup vs baseline: 1.3838x; 1.3838x over previous
//
#include <hip/hip_runtime.h>
#include <math.h>

#define NNODES 50000
#define NEDGES 800000
#define NLAYERS 3
#define NHEADS 2
#define NCH 64
#define FDIM 128   // == NHEADS*NCH
#define NCLS 10
#define NGRAPH 64
#define NEG_SLOPE 0.2f
#define NBLK ((NNODES + 255) / 256)   // 196

#define WAVE_SYNC()                      \
  do {                                   \
    __builtin_amdgcn_wave_barrier();     \
    __asm__ volatile("" ::: "memory");   \
  } while (0)

// ---------------- CSR build ----------------

__global__ void k_init(int* __restrict__ deg, float* __restrict__ gsum,
                       float* __restrict__ gcnt) {
  int i = blockIdx.x * 256 + threadIdx.x;
  if (i < NNODES) deg[i] = 1;              // seed with the self-loop
  if (i < NGRAPH * FDIM) gsum[i] = 0.f;
  if (i < NGRAPH) gcnt[i] = 0.f;
}

__global__ void k_hist(const int* __restrict__ ei, int* __restrict__ deg) {
  int e = blockIdx.x * 256 + threadIdx.x;
  if (e < NEDGES) atomicAdd(&deg[ei[NEDGES + e]], 1);
}

// per-block exclusive scan; block total -> bsum
__global__ __launch_bounds__(256) void k_scan1(const int* __restrict__ deg,
                                               int* __restrict__ pre,
                                               int* __restrict__ bsum) {
  __shared__ int ps[256];
  int t = threadIdx.x;
  int i = blockIdx.x * 256 + t;
  int c = (i < NNODES) ? deg[i] : 0;
  ps[t] = c;
  __syncthreads();
  for (int off = 1; off < 256; off <<= 1) {
    int v = (t >= off) ? ps[t - off] : 0;
    __syncthreads();
    ps[t] += v;
    __syncthreads();
  }
  if (i < NNODES) pre[i] = ps[t] - c;
  if (t == 255) bsum[blockIdx.x] = ps[255];
}

// scan the 196 block sums (one block)
__global__ __launch_bounds__(256) void k_scan2(const int* __restrict__ bsum,
                                               int* __restrict__ boff) {
  __shared__ int ps[256];
  int t = threadIdx.x;
  int c = (t < NBLK) ? bsum[t] : 0;
  ps[t] = c;
  __syncthreads();
  for (int off = 1; off < 256; off <<= 1) {
    int v = (t >= off) ? ps[t - off] : 0;
    __syncthreads();
    ps[t] += v;
    __syncthreads();
  }
  if (t < NBLK) boff[t] = ps[t] - c;
}

__global__ void k_scan3(const int* __restrict__ pre,
                        const int* __restrict__ boff,
                        int* __restrict__ row_ptr, int* __restrict__ cursor) {
  int i = blockIdx.x * 256 + threadIdx.x;
  if (i < NNODES) {
    int o = pre[i] + boff[i >> 8];
    row_ptr[i] = o;
    cursor[i] = o;
  }
  if (i == 0) row_ptr[NNODES] = NEDGES + NNODES;
}

__global__ void k_scatter(const int* __restrict__ ei, int* __restrict__ cursor,
                          int* __restrict__ csr) {
  int t = blockIdx.x * 256 + threadIdx.x;
  if (t < NEDGES) {
    int s = ei[t];
    int d = ei[NEDGES + t];
    int pos = atomicAdd(&cursor[d], 1);
    csr[pos] = s;
  } else if (t < NEDGES + NNODES) {
    int i = t - NEDGES;           // self-loop
    int pos = atomicAdd(&cursor[i], 1);
    csr[pos] = i;
  }
}

// ---------------- per-layer kernels ----------------

// H[row,:] = X[row,:] @ Wg (128x128), fp32; alpha_src/dst fused in epilogue.
__global__ __launch_bounds__(256) void k_gemm(const float* __restrict__ X,
                                              const float* __restrict__ Wg,
                                              const float* __restrict__ a_sL,
                                              const float* __restrict__ a_dL,
                                              float* __restrict__ H,
                                              float* __restrict__ as_,
                                              float* __restrict__ ad_) {
  __shared__ float Xs[64][33];
  __shared__ float Ws[32][128];
  int t = threadIdx.x;
  int row0 = blockIdx.x * 64;
  int col = (t & 31) * 4;
  int rbase = (t >> 5) * 8;
  float acc[8][4];
#pragma unroll
  for (int i = 0; i < 8; ++i)
#pragma unroll
    for (int j = 0; j < 4; ++j) acc[i][j] = 0.f;

  for (int k0 = 0; k0 < 128; k0 += 32) {
    {  // stage X tile (64 rows x 32 k)
      int xr = t >> 2, xk = (t & 3) * 8;
      int gr = row0 + xr;
      float4 v0 = make_float4(0.f, 0.f, 0.f, 0.f), v1 = v0;
      if (gr < NNODES) {
        const float* p = X + (size_t)gr * 128 + k0 + xk;
        v0 = *(const float4*)p;
        v1 = *(const float4*)(p + 4);
      }
      Xs[xr][xk + 0] = v0.x; Xs[xr][xk + 1] = v0.y;
      Xs[xr][xk + 2] = v0.z; Xs[xr][xk + 3] = v0.w;
      Xs[xr][xk + 4] = v1.x; Xs[xr][xk + 5] = v1.y;
      Xs[xr][xk + 6] = v1.z; Xs[xr][xk + 7] = v1.w;
    }
    {  // stage W tile (32 k x 128 cols)
      int wr = t >> 3, wc = (t & 7) * 16;
      const float* p = Wg + (size_t)(k0 + wr) * 128 + wc;
#pragma unroll
      for (int j = 0; j < 4; ++j) {
        float4 v = *(const float4*)(p + 4 * j);
        *(float4*)&Ws[wr][wc + 4 * j] = v;
      }
    }
    __syncthreads();
#pragma unroll
    for (int kk = 0; kk < 32; ++kk) {
      float4 b = *(const float4*)&Ws[kk][col];
#pragma unroll
      for (int i = 0; i < 8; ++i) {
        float a = Xs[rbase + i][kk];
        acc[i][0] += a * b.x;
        acc[i][1] += a * b.y;
        acc[i][2] += a * b.z;
        acc[i][3] += a * b.w;
      }
    }
    __syncthreads();
  }

  // epilogue: write H and fused alpha_src / alpha_dst
  float4 asv = *(const float4*)&a_sL[col];
  float4 adv = *(const float4*)&a_dL[col];
  int head = (t >> 4) & 1;  // (t&31)>>4
#pragma unroll
  for (int i = 0; i < 8; ++i) {
    int r = row0 + rbase + i;
    bool ok = (r < NNODES);
    if (ok) {
      float4 v = make_float4(acc[i][0], acc[i][1], acc[i][2], acc[i][3]);
      *(float4*)&H[(size_t)r * 128 + col] = v;
    }
    // dot with attention vectors, reduce over the 16 lanes of this head
    float ps = acc[i][0] * asv.x + acc[i][1] * asv.y + acc[i][2] * asv.z +
               acc[i][3] * asv.w;
    float pd = acc[i][0] * adv.x + acc[i][1] * adv.y + acc[i][2] * adv.z +
               acc[i][3] * adv.w;
#pragma unroll
    for (int off = 8; off > 0; off >>= 1) {
      ps += __shfl_xor(ps, off, 64);
      pd += __shfl_xor(pd, off, 64);
    }
    if (ok && (t & 15) == 0) {
      as_[r * 2 + head] = ps;
      ad_[r * 2 + head] = pd;
    }
  }
}

// One wave per node: softmax (shift-invariant, no max pass) + aggregation.
__global__ __launch_bounds__(256) void k_aggregate(
    const float* __restrict__ H, const float* __restrict__ as_,
    const float* __restrict__ ad_, const int* __restrict__ row_ptr,
    const int* __restrict__ csr, const float* __restrict__ bias,
    float* __restrict__ Xout) {
  __shared__ float2 wb[4][64];
  __shared__ int sb[4][64];
  int wv = threadIdx.x >> 6;
  int lane = threadIdx.x & 63;
  int node = blockIdx.x * 4 + wv;
  if (node >= NNODES) return;
  int rs = row_ptr[node], re = row_ptr[node + 1];
  float2 adv = *(const float2*)&ad_[node * 2];

  float z0 = 0.f, z1 = 0.f, acc0 = 0.f, acc1 = 0.f;
  for (int base = rs; base < re; base += 64) {
    int j = base + lane;
    float p0 = 0.f, p1 = 0.f;
    int s = 0;
    if (j < re) {
      s = csr[j];
      float2 asv = *(const float2*)&as_[s * 2];
      float e0 = asv.x + adv.x; e0 = (e0 > 0.f) ? e0 : NEG_SLOPE * e0;
      float e1 = asv.y + adv.y; e1 = (e1 > 0.f) ? e1 : NEG_SLOPE * e1;
      p0 = __expf(e0);
      p1 = __expf(e1);
    }
    z0 += p0;
    z1 += p1;
    wb[wv][lane] = make_float2(p0, p1);
    sb[wv][lane] = s;
    WAVE_SYNC();
    int cl = min(64, re - base);
    int jj = 0;
    for (; jj + 4 <= cl; jj += 4) {
      int s0 = sb[wv][jj + 0], s1 = sb[wv][jj + 1];
      int s2 = sb[wv][jj + 2], s3 = sb[wv][jj + 3];
      float2 w0 = wb[wv][jj + 0], w1 = wb[wv][jj + 1];
      float2 w2 = wb[wv][jj + 2], w3 = wb[wv][jj + 3];
      const float* h0 = H + (size_t)s0 * 128 + lane;
      const float* h1 = H + (size_t)s1 * 128 + lane;
      const float* h2 = H + (size_t)s2 * 128 + lane;
      const float* h3 = H + (size_t)s3 * 128 + lane;
      float a0 = h0[0], b0 = h0[64];
      float a1 = h1[0], b1 = h1[64];
      float a2 = h2[0], b2 = h2[64];
      float a3 = h3[0], b3 = h3[64];
      acc0 += w0.x * a0; acc1 += w0.y * b0;
      acc0 += w1.x * a1; acc1 += w1.y * b1;
      acc0 += w2.x * a2; acc1 += w2.y * b2;
      acc0 += w3.x * a3; acc1 += w3.y * b3;
    }
    for (; jj < cl; ++jj) {
      int ss = sb[wv][jj];
      float2 w = wb[wv][jj];
      const float* hp = H + (size_t)ss * 128 + lane;
      acc0 += w.x * hp[0];
      acc1 += w.y * hp[64];
    }
    WAVE_SYNC();
  }
#pragma unroll
  for (int off = 32; off > 0; off >>= 1) {
    z0 += __shfl_xor(z0, off, 64);
    z1 += __shfl_xor(z1, off, 64);
  }
  float o0 = acc0 / z0 + bias[lane];
  float o1 = acc1 / z1 + bias[64 + lane];
  o0 = (o0 > 0.f) ? o0 : expm1f(o0);  // ELU
  o1 = (o1 > 0.f) ? o1 : expm1f(o1);
  Xout[(size_t)node * 128 + lane] = o0;
  Xout[(size_t)node * 128 + 64 + lane] = o1;
}

// ---------------- pooling + classifier ----------------

__global__ __launch_bounds__(128) void k_pool(const float* __restrict__ Xf,
                                              const int* __restrict__ batch,
                                              float* __restrict__ gsum) {
  int c = threadIdx.x;
  int n0 = blockIdx.x * 64;
  if (n0 >= NNODES) return;
  int n1 = min(n0 + 64, NNODES);
  int cur = batch[n0];
  float acc = 0.f;
  for (int n = n0; n < n1; ++n) {
    int g = batch[n];
    if (g != cur) {
      atomicAdd(&gsum[cur * FDIM + c], acc);
      acc = 0.f;
      cur = g;
    }
    acc += Xf[(size_t)n * 128 + c];
  }
  atomicAdd(&gsum[cur * FDIM + c], acc);
}

__global__ __launch_bounds__(256) void k_cnt(const int* __restrict__ batch,
                                             float* __restrict__ gcnt) {
  __shared__ float loc[NGRAPH];
  int t = threadIdx.x;
  if (t < NGRAPH) loc[t] = 0.f;
  __syncthreads();
  int n = blockIdx.x * 256 + t;
  if (n < NNODES) atomicAdd(&loc[batch[n]], 1.f);
  __syncthreads();
  if (t < NGRAPH && loc[t] > 0.f) atomicAdd(&gcnt[t], loc[t]);
}

__global__ __launch_bounds__(64) void k_final(const float* __restrict__ gsum,
                                              const float* __restrict__ gcnt,
                                              const float* __restrict__ lw,
                                              const float* __restrict__ lb,
                                              float* __restrict__ out) {
  int g = threadIdx.x;
  float inv = 1.f / fmaxf(gcnt[g], 1.f);
  float lg[NCLS];
#pragma unroll
  for (int k = 0; k < NCLS; ++k) lg[k] = lb[k];
  for (int c = 0; c < FDIM; ++c) {
    float pv = gsum[g * FDIM + c] * inv;
#pragma unroll
    for (int k = 0; k < NCLS; ++k) lg[k] += pv * lw[c * NCLS + k];
  }
  float mx = lg[0];
#pragma unroll
  for (int k = 1; k < NCLS; ++k) mx = fmaxf(mx, lg[k]);
  float s = 0.f;
#pragma unroll
  for (int k = 0; k < NCLS; ++k) {
    lg[k] = expf(lg[k] - mx);
    s += lg[k];
  }
  float invs = 1.f / s;
#pragma unroll
  for (int k = 0; k < NCLS; ++k) out[g * NCLS + k] = lg[k] * invs;
}

// ---------------- launch ----------------

extern "C" void kernel_launch(void* const* d_in, const int* in_sizes, int n_in,
                              void* d_out, int out_size, void* d_ws,
                              size_t ws_size, hipStream_t stream) {
  const float* x = (const float*)d_in[0];
  const int* ei = (const int*)d_in[1];
  const int* batch = (const int*)d_in[2];
  const float* W = (const float*)d_in[3];
  const float* a_s = (const float*)d_in[4];
  const float* a_d = (const float*)d_in[5];
  const float* bias = (const float*)d_in[6];
  const float* lw = (const float*)d_in[7];
  const float* lb = (const float*)d_in[8];
  float* out = (float*)d_out;

  float* ws = (float*)d_ws;
  float* h = ws;                                   // N*128
  float* xb = h + (size_t)NNODES * 128;            // N*128
  float* as_ = xb + (size_t)NNODES * 128;          // N*2
  float* ad_ = as_ + (size_t)NNODES * 2;           // N*2
  float* gsum = ad_ + (size_t)NNODES * 2;          // 64*128
  float* gcnt = gsum + NGRAPH * FDIM;              // 64
  int* row_ptr = (int*)(gcnt + NGRAPH);            // N+1
  int* cursor = row_ptr + (NNODES + 1);            // N
  int* csr = cursor + NNODES;                      // E+N
  int* deg = csr + (NEDGES + NNODES);              // N
  int* pre = deg + NNODES;                         // N
  int* bsum = pre + NNODES;                        // NBLK
  int* boff = bsum + NBLK;                         // NBLK

  // CSR build (graph is layer-invariant)
  k_init<<<(NNODES + 255) / 256, 256, 0, stream>>>(deg, gsum, gcnt);
  k_hist<<<(NEDGES + 255) / 256, 256, 0, stream>>>(ei, deg);
  k_scan1<<<NBLK, 256, 0, stream>>>(deg, pre, bsum);
  k_scan2<<<1, 256, 0, stream>>>(bsum, boff);
  k_scan3<<<NBLK, 256, 0, stream>>>(pre, boff, row_ptr, cursor);
  k_scatter<<<(NEDGES + NNODES + 255) / 256, 256, 0, stream>>>(ei, cursor, csr);

  const float* xin = x;
  for (int l = 0; l < NLAYERS; ++l) {
    k_gemm<<<(NNODES + 63) / 64, 256, 0, stream>>>(
        xin, W + l * FDIM * FDIM, a_s + l * FDIM, a_d + l * FDIM, h, as_, ad_);
    k_aggregate<<<(NNODES + 3) / 4, 256, 0, stream>>>(
        h, as_, ad_, row_ptr, csr, bias + l * FDIM, xb);
    xin = xb;
  }
  k_pool<<<(NNODES + 63) / 64, 128, 0, stream>>>(xb, batch, gsum);
  k_cnt<<<(NNODES + 255) / 256, 256, 0, stream>>>(batch, gcnt);
  k_final<<<1, 64, 0, stream>>>(gsum, gcnt, lw, lb, out);
}

// Round 3
// 357.598 us; speedup vs baseline: 1.9292x; 1.3942x over previous
//
#include <hip/hip_runtime.h>
#include <math.h>

#define NNODES 50000
#define NEDGES 800000
#define NLAYERS 3
#define NHEADS 2
#define NCH 64
#define FDIM 128   // == NHEADS*NCH
#define NCLS 10
#define NGRAPH 64
#define NEG_SLOPE 0.2f
#define NBLK ((NNODES + 255) / 256)   // 196
#define GEMMB ((NNODES + 63) / 64)    // 782
#define HISTB ((NEDGES + 255) / 256)  // 3125

#define WAVE_SYNC()                      \
  do {                                   \
    __builtin_amdgcn_wave_barrier();     \
    __asm__ volatile("" ::: "memory");   \
  } while (0)

__device__ __forceinline__ unsigned short f2bf(float f) {
  unsigned int u = __builtin_bit_cast(unsigned int, f);
  unsigned int r = u + 0x7FFFu + ((u >> 16) & 1u);  // RNE
  return (unsigned short)(r >> 16);
}
__device__ __forceinline__ float bflo(unsigned v) {
  return __builtin_bit_cast(float, v << 16);
}
__device__ __forceinline__ float bfhi(unsigned v) {
  return __builtin_bit_cast(float, v & 0xFFFF0000u);
}

// ---------------- CSR build ----------------

__global__ void k_init(int* __restrict__ deg, float* __restrict__ gsum,
                       float* __restrict__ gcnt) {
  int i = blockIdx.x * 256 + threadIdx.x;
  if (i < NNODES) deg[i] = 1;              // seed: self-loop occupies rank 0
  if (i < NGRAPH * FDIM) gsum[i] = 0.f;
  if (i < NGRAPH) gcnt[i] = 0.f;
}

// per-block exclusive scan; block total -> bsum
__global__ __launch_bounds__(256) void k_scan1(const int* __restrict__ deg,
                                               int* __restrict__ pre,
                                               int* __restrict__ bsum) {
  __shared__ int ps[256];
  int t = threadIdx.x;
  int i = blockIdx.x * 256 + t;
  int c = (i < NNODES) ? deg[i] : 0;
  ps[t] = c;
  __syncthreads();
  for (int off = 1; off < 256; off <<= 1) {
    int v = (t >= off) ? ps[t - off] : 0;
    __syncthreads();
    ps[t] += v;
    __syncthreads();
  }
  if (i < NNODES) pre[i] = ps[t] - c;
  if (t == 255) bsum[blockIdx.x] = ps[255];
}

__global__ __launch_bounds__(256) void k_scan2(const int* __restrict__ bsum,
                                               int* __restrict__ boff) {
  __shared__ int ps[256];
  int t = threadIdx.x;
  int c = (t < NBLK) ? bsum[t] : 0;
  ps[t] = c;
  __syncthreads();
  for (int off = 1; off < 256; off <<= 1) {
    int v = (t >= off) ? ps[t - off] : 0;
    __syncthreads();
    ps[t] += v;
    __syncthreads();
  }
  if (t < NBLK) boff[t] = ps[t] - c;
}

__global__ void k_scan3(const int* __restrict__ pre,
                        const int* __restrict__ boff,
                        int* __restrict__ row_ptr, int* __restrict__ csr) {
  int i = blockIdx.x * 256 + threadIdx.x;
  if (i < NNODES) {
    int o = pre[i] + boff[i >> 8];
    row_ptr[i] = o;
    csr[o] = i;  // self-loop at rank 0
  }
  if (i == 0) row_ptr[NNODES] = NEDGES + NNODES;
}

// atomic-free scatter using precomputed ranks
__global__ void k_scatter(const int* __restrict__ ei,
                          const int* __restrict__ row_ptr,
                          const int* __restrict__ rank, int* __restrict__ csr) {
  int e = blockIdx.x * 256 + threadIdx.x;
  if (e < NEDGES) {
    int d = ei[NEDGES + e];
    csr[row_ptr[d] + rank[e]] = ei[e];
  }
}

// ---------------- GEMM body (shared by front + later layers) ----------------
// H[row,:] = X[row,:] @ Wg (128x128) fp32 accum; writes packed-bf16 Hb and
// fused alpha_src / alpha_dst.
__device__ __forceinline__ void gemm_body(int blk, const float* __restrict__ X,
                                          const float* __restrict__ Wg,
                                          const float* __restrict__ a_sL,
                                          const float* __restrict__ a_dL,
                                          unsigned* __restrict__ Hb,
                                          float* __restrict__ as_,
                                          float* __restrict__ ad_) {
  __shared__ float Xs[64][33];
  __shared__ float Ws[32][128];
  int t = threadIdx.x;
  int lane = t & 63;
  int row0 = blk * 64;
  int col = (t & 31) * 4;
  int rbase = (t >> 5) * 8;
  float acc[8][4];
#pragma unroll
  for (int i = 0; i < 8; ++i)
#pragma unroll
    for (int j = 0; j < 4; ++j) acc[i][j] = 0.f;

  for (int k0 = 0; k0 < 128; k0 += 32) {
    {  // stage X tile (64 rows x 32 k)
      int xr = t >> 2, xk = (t & 3) * 8;
      int gr = row0 + xr;
      float4 v0 = make_float4(0.f, 0.f, 0.f, 0.f), v1 = v0;
      if (gr < NNODES) {
        const float* p = X + (size_t)gr * 128 + k0 + xk;
        v0 = *(const float4*)p;
        v1 = *(const float4*)(p + 4);
      }
      Xs[xr][xk + 0] = v0.x; Xs[xr][xk + 1] = v0.y;
      Xs[xr][xk + 2] = v0.z; Xs[xr][xk + 3] = v0.w;
      Xs[xr][xk + 4] = v1.x; Xs[xr][xk + 5] = v1.y;
      Xs[xr][xk + 6] = v1.z; Xs[xr][xk + 7] = v1.w;
    }
    {  // stage W tile (32 k x 128 cols)
      int wr = t >> 3, wc = (t & 7) * 16;
      const float* p = Wg + (size_t)(k0 + wr) * 128 + wc;
#pragma unroll
      for (int j = 0; j < 4; ++j) {
        float4 v = *(const float4*)(p + 4 * j);
        *(float4*)&Ws[wr][wc + 4 * j] = v;
      }
    }
    __syncthreads();
#pragma unroll
    for (int kk = 0; kk < 32; ++kk) {
      float4 b = *(const float4*)&Ws[kk][col];
#pragma unroll
      for (int i = 0; i < 8; ++i) {
        float a = Xs[rbase + i][kk];
        acc[i][0] += a * b.x;
        acc[i][1] += a * b.y;
        acc[i][2] += a * b.z;
        acc[i][3] += a * b.w;
      }
    }
    __syncthreads();
  }

  // epilogue: packed-bf16 H write + fused alpha_src / alpha_dst
  float4 asv = *(const float4*)&a_sL[col];
  float4 adv = *(const float4*)&a_dL[col];
  int head = (t >> 4) & 1;
#pragma unroll
  for (int i = 0; i < 8; ++i) {
    int r = row0 + rbase + i;
    bool ok = (r < NNODES);
    float ps = acc[i][0] * asv.x + acc[i][1] * asv.y + acc[i][2] * asv.z +
               acc[i][3] * asv.w;
    float pd = acc[i][0] * adv.x + acc[i][1] * adv.y + acc[i][2] * adv.z +
               acc[i][3] * adv.w;
#pragma unroll
    for (int off = 8; off > 0; off >>= 1) {
      ps += __shfl_xor(ps, off, 64);
      pd += __shfl_xor(pd, off, 64);
    }
    if (ok && (t & 15) == 0) {
      as_[r * 2 + head] = ps;
      ad_[r * 2 + head] = pd;
    }
    // pack (h[c], h[c+64]) into one uint; partner lane (+16) holds col+64
    unsigned pk[4];
#pragma unroll
    for (int j = 0; j < 4; ++j) {
      float hi = __shfl(acc[i][j], (lane + 16) & 63, 64);
      pk[j] = (unsigned)f2bf(acc[i][j]) | ((unsigned)f2bf(hi) << 16);
    }
    if (ok && (t & 31) < 16) {
      *(uint4*)&Hb[(size_t)r * 64 + col] =
          make_uint4(pk[0], pk[1], pk[2], pk[3]);
    }
  }
}

__global__ __launch_bounds__(256) void k_gemm(const float* __restrict__ X,
                                              const float* __restrict__ Wg,
                                              const float* __restrict__ a_sL,
                                              const float* __restrict__ a_dL,
                                              unsigned* __restrict__ Hb,
                                              float* __restrict__ as_,
                                              float* __restrict__ ad_) {
  gemm_body(blockIdx.x, X, Wg, a_sL, a_dL, Hb, as_, ad_);
}

// fused: layer-0 GEMM | edge histogram (+rank) | per-graph node count.
// The three segments are independent; branch is block-uniform.
__global__ __launch_bounds__(256) void k_front(
    const float* __restrict__ X, const float* __restrict__ Wg,
    const float* __restrict__ a_sL, const float* __restrict__ a_dL,
    unsigned* __restrict__ Hb, float* __restrict__ as_,
    float* __restrict__ ad_, const int* __restrict__ ei, int* __restrict__ deg,
    int* __restrict__ rank, const int* __restrict__ batch,
    float* __restrict__ gcnt) {
  int b = blockIdx.x;
  if (b < GEMMB) {
    gemm_body(b, X, Wg, a_sL, a_dL, Hb, as_, ad_);
  } else if (b < GEMMB + HISTB) {
    int e = (b - GEMMB) * 256 + threadIdx.x;
    if (e < NEDGES) rank[e] = atomicAdd(&deg[ei[NEDGES + e]], 1);
  } else {
    __shared__ float loc[NGRAPH];
    int t = threadIdx.x;
    if (t < NGRAPH) loc[t] = 0.f;
    __syncthreads();
    int n = (b - GEMMB - HISTB) * 256 + t;
    if (n < NNODES) atomicAdd(&loc[batch[n]], 1.f);
    __syncthreads();
    if (t < NGRAPH && loc[t] > 0.f) atomicAdd(&gcnt[t], loc[t]);
  }
}

// One wave per node: softmax (shift-invariant, no max pass) + aggregation.
__global__ __launch_bounds__(256) void k_aggregate(
    const unsigned* __restrict__ Hb, const float* __restrict__ as_,
    const float* __restrict__ ad_, const int* __restrict__ row_ptr,
    const int* __restrict__ csr, const float* __restrict__ bias,
    float* __restrict__ Xout) {
  __shared__ float2 wb[4][64];
  __shared__ int sb[4][64];
  int wv = threadIdx.x >> 6;
  int lane = threadIdx.x & 63;
  int node = blockIdx.x * 4 + wv;
  if (node >= NNODES) return;
  int rs = row_ptr[node], re = row_ptr[node + 1];
  float2 adv = *(const float2*)&ad_[node * 2];

  float z0 = 0.f, z1 = 0.f, acc0 = 0.f, acc1 = 0.f;
  for (int base = rs; base < re; base += 64) {
    int j = base + lane;
    float p0 = 0.f, p1 = 0.f;
    int s = 0;
    if (j < re) {
      s = csr[j];
      float2 asv = *(const float2*)&as_[s * 2];
      float e0 = asv.x + adv.x; e0 = (e0 > 0.f) ? e0 : NEG_SLOPE * e0;
      float e1 = asv.y + adv.y; e1 = (e1 > 0.f) ? e1 : NEG_SLOPE * e1;
      p0 = __expf(e0);
      p1 = __expf(e1);
    }
    z0 += p0;
    z1 += p1;
    wb[wv][lane] = make_float2(p0, p1);
    sb[wv][lane] = s;
    WAVE_SYNC();
    int cl = min(64, re - base);
    int jj = 0;
    for (; jj + 4 <= cl; jj += 4) {
      int s0 = sb[wv][jj + 0], s1 = sb[wv][jj + 1];
      int s2 = sb[wv][jj + 2], s3 = sb[wv][jj + 3];
      float2 w0 = wb[wv][jj + 0], w1 = wb[wv][jj + 1];
      float2 w2 = wb[wv][jj + 2], w3 = wb[wv][jj + 3];
      unsigned v0 = Hb[(size_t)s0 * 64 + lane];
      unsigned v1 = Hb[(size_t)s1 * 64 + lane];
      unsigned v2 = Hb[(size_t)s2 * 64 + lane];
      unsigned v3 = Hb[(size_t)s3 * 64 + lane];
      acc0 += w0.x * bflo(v0); acc1 += w0.y * bfhi(v0);
      acc0 += w1.x * bflo(v1); acc1 += w1.y * bfhi(v1);
      acc0 += w2.x * bflo(v2); acc1 += w2.y * bfhi(v2);
      acc0 += w3.x * bflo(v3); acc1 += w3.y * bfhi(v3);
    }
    for (; jj < cl; ++jj) {
      int ss = sb[wv][jj];
      float2 w = wb[wv][jj];
      unsigned v = Hb[(size_t)ss * 64 + lane];
      acc0 += w.x * bflo(v);
      acc1 += w.y * bfhi(v);
    }
    WAVE_SYNC();
  }
#pragma unroll
  for (int off = 32; off > 0; off >>= 1) {
    z0 += __shfl_xor(z0, off, 64);
    z1 += __shfl_xor(z1, off, 64);
  }
  float o0 = acc0 / z0 + bias[lane];
  float o1 = acc1 / z1 + bias[64 + lane];
  o0 = (o0 > 0.f) ? o0 : expm1f(o0);  // ELU
  o1 = (o1 > 0.f) ? o1 : expm1f(o1);
  Xout[(size_t)node * 128 + lane] = o0;
  Xout[(size_t)node * 128 + 64 + lane] = o1;
}

// ---------------- pooling + classifier ----------------

__global__ __launch_bounds__(128) void k_pool(const float* __restrict__ Xf,
                                              const int* __restrict__ batch,
                                              float* __restrict__ gsum) {
  int c = threadIdx.x;
  int n0 = blockIdx.x * 64;
  if (n0 >= NNODES) return;
  int n1 = min(n0 + 64, NNODES);
  int cur = batch[n0];
  float acc = 0.f;
  for (int n = n0; n < n1; ++n) {
    int g = batch[n];
    if (g != cur) {
      atomicAdd(&gsum[cur * FDIM + c], acc);
      acc = 0.f;
      cur = g;
    }
    acc += Xf[(size_t)n * 128 + c];
  }
  atomicAdd(&gsum[cur * FDIM + c], acc);
}

__global__ __launch_bounds__(64) void k_final(const float* __restrict__ gsum,
                                              const float* __restrict__ gcnt,
                                              const float* __restrict__ lw,
                                              const float* __restrict__ lb,
                                              float* __restrict__ out) {
  int g = threadIdx.x;
  float inv = 1.f / fmaxf(gcnt[g], 1.f);
  float lg[NCLS];
#pragma unroll
  for (int k = 0; k < NCLS; ++k) lg[k] = lb[k];
  for (int c = 0; c < FDIM; ++c) {
    float pv = gsum[g * FDIM + c] * inv;
#pragma unroll
    for (int k = 0; k < NCLS; ++k) lg[k] += pv * lw[c * NCLS + k];
  }
  float mx = lg[0];
#pragma unroll
  for (int k = 1; k < NCLS; ++k) mx = fmaxf(mx, lg[k]);
  float s = 0.f;
#pragma unroll
  for (int k = 0; k < NCLS; ++k) {
    lg[k] = expf(lg[k] - mx);
    s += lg[k];
  }
  float invs = 1.f / s;
#pragma unroll
  for (int k = 0; k < NCLS; ++k) out[g * NCLS + k] = lg[k] * invs;
}

// ---------------- launch ----------------

extern "C" void kernel_launch(void* const* d_in, const int* in_sizes, int n_in,
                              void* d_out, int out_size, void* d_ws,
                              size_t ws_size, hipStream_t stream) {
  const float* x = (const float*)d_in[0];
  const int* ei = (const int*)d_in[1];
  const int* batch = (const int*)d_in[2];
  const float* W = (const float*)d_in[3];
  const float* a_s = (const float*)d_in[4];
  const float* a_d = (const float*)d_in[5];
  const float* bias = (const float*)d_in[6];
  const float* lw = (const float*)d_in[7];
  const float* lb = (const float*)d_in[8];
  float* out = (float*)d_out;

  unsigned* Hb = (unsigned*)d_ws;                  // N*64 packed bf16 pairs
  float* xb = (float*)(Hb + (size_t)NNODES * 64);  // N*128
  float* as_ = xb + (size_t)NNODES * 128;          // N*2
  float* ad_ = as_ + (size_t)NNODES * 2;           // N*2
  float* gsum = ad_ + (size_t)NNODES * 2;          // 64*128
  float* gcnt = gsum + NGRAPH * FDIM;              // 64
  int* row_ptr = (int*)(gcnt + NGRAPH);            // N+1
  int* csr = row_ptr + (NNODES + 1);               // E+N
  int* deg = csr + (NEDGES + NNODES);              // N
  int* pre = deg + NNODES;                         // N
  int* bsum = pre + NNODES;                        // NBLK
  int* boff = bsum + NBLK;                         // NBLK
  int* rank = boff + NBLK;                         // E

  k_init<<<(NNODES + 255) / 256, 256, 0, stream>>>(deg, gsum, gcnt);
  // layer-0 GEMM overlapped with edge histogram + graph-size count
  k_front<<<GEMMB + HISTB + NBLK, 256, 0, stream>>>(
      x, W, a_s, a_d, Hb, as_, ad_, ei, deg, rank, batch, gcnt);
  k_scan1<<<NBLK, 256, 0, stream>>>(deg, pre, bsum);
  k_scan2<<<1, 256, 0, stream>>>(bsum, boff);
  k_scan3<<<NBLK, 256, 0, stream>>>(pre, boff, row_ptr, csr);
  k_scatter<<<HISTB, 256, 0, stream>>>(ei, row_ptr, rank, csr);

  for (int l = 0; l < NLAYERS; ++l) {
    if (l > 0) {
      k_gemm<<<GEMMB, 256, 0, stream>>>(xb, W + l * FDIM * FDIM,
                                        a_s + l * FDIM, a_d + l * FDIM, Hb,
                                        as_, ad_);
    }
    k_aggregate<<<(NNODES + 3) / 4, 256, 0, stream>>>(
        Hb, as_, ad_, row_ptr, csr, bias + l * FDIM, xb);
  }
  k_pool<<<(NNODES + 63) / 64, 128, 0, stream>>>(xb, batch, gsum);
  k_final<<<1, 64, 0, stream>>>(gsum, gcnt, lw, lb, out);
}

// Round 4
// 334.589 us; speedup vs baseline: 2.0619x; 1.0688x over previous
//
#include <hip/hip_runtime.h>
#include <math.h>

#define NNODES 50000
#define NEDGES 800000
#define NLAYERS 3
#define NHEADS 2
#define NCH 64
#define FDIM 128   // == NHEADS*NCH
#define NCLS 10
#define NGRAPH 64
#define NEG_SLOPE 0.2f
#define NBLK ((NNODES + 255) / 256)   // 196
#define GEMMB ((NNODES + 63) / 64)    // 782
#define HISTB ((NEDGES + 255) / 256)  // 3125

#define WAVE_SYNC()                      \
  do {                                   \
    __builtin_amdgcn_wave_barrier();     \
    __asm__ volatile("" ::: "memory");   \
  } while (0)

typedef __attribute__((ext_vector_type(8))) short bf16x8;
typedef __attribute__((ext_vector_type(4))) float f32x4;

__device__ __forceinline__ unsigned short f2bf(float f) {
  unsigned int u = __builtin_bit_cast(unsigned int, f);
  unsigned int r = u + 0x7FFFu + ((u >> 16) & 1u);  // RNE
  return (unsigned short)(r >> 16);
}
__device__ __forceinline__ float bflo(unsigned v) {
  return __builtin_bit_cast(float, v << 16);
}
__device__ __forceinline__ float bfhi(unsigned v) {
  return __builtin_bit_cast(float, v & 0xFFFF0000u);
}

// ---------------- W prep: transpose + bf16 (3 blocks, one per layer) -------
__global__ __launch_bounds__(256) void k_wprep(const float* __restrict__ W,
                                               unsigned* __restrict__ Wt) {
  __shared__ float Lt[128][132];
  int l = blockIdx.x;
  const float* Wl = W + (size_t)l * FDIM * FDIM;
  unsigned* Wtl = Wt + (size_t)l * FDIM * FDIM / 2;
  int t = threadIdx.x;
#pragma unroll
  for (int i = 0; i < 16; ++i) {
    int k = (t >> 5) + 8 * i;
    int n4 = (t & 31) * 4;
    float4 v = *(const float4*)(Wl + (size_t)k * 128 + n4);
    Lt[k][n4 + 0] = v.x;
    Lt[k][n4 + 1] = v.y;
    Lt[k][n4 + 2] = v.z;
    Lt[k][n4 + 3] = v.w;
  }
  __syncthreads();
  int n = t >> 1;
  int kh = (t & 1) * 64;
  for (int kk = 0; kk < 64; kk += 2) {
    unsigned pk = (unsigned)f2bf(Lt[kh + kk][n]) |
                  ((unsigned)f2bf(Lt[kh + kk + 1][n]) << 16);
    Wtl[n * 64 + (kh >> 1) + (kk >> 1)] = pk;
  }
}

// ---------------- CSR build ----------------

// per-block exclusive scan of (deg+1); block total -> bsum
__global__ __launch_bounds__(256) void k_scan1(const int* __restrict__ deg,
                                               int* __restrict__ pre,
                                               int* __restrict__ bsum) {
  __shared__ int ps[256];
  int t = threadIdx.x;
  int i = blockIdx.x * 256 + t;
  int c = (i < NNODES) ? (deg[i] + 1) : 0;  // +1: self-loop
  ps[t] = c;
  __syncthreads();
  for (int off = 1; off < 256; off <<= 1) {
    int v = (t >= off) ? ps[t - off] : 0;
    __syncthreads();
    ps[t] += v;
    __syncthreads();
  }
  if (i < NNODES) pre[i] = ps[t] - c;
  if (t == 255) bsum[blockIdx.x] = ps[255];
}

__global__ __launch_bounds__(256) void k_scan2(const int* __restrict__ bsum,
                                               int* __restrict__ boff) {
  __shared__ int ps[256];
  int t = threadIdx.x;
  int c = (t < NBLK) ? bsum[t] : 0;
  ps[t] = c;
  __syncthreads();
  for (int off = 1; off < 256; off <<= 1) {
    int v = (t >= off) ? ps[t - off] : 0;
    __syncthreads();
    ps[t] += v;
    __syncthreads();
  }
  if (t < NBLK) boff[t] = ps[t] - c;
}

__global__ void k_scan3(const int* __restrict__ pre,
                        const int* __restrict__ boff,
                        int* __restrict__ row_ptr, int* __restrict__ csr) {
  int i = blockIdx.x * 256 + threadIdx.x;
  if (i < NNODES) {
    int o = pre[i] + boff[i >> 8];
    row_ptr[i] = o;
    csr[o] = i;  // self-loop at rank 0
  }
  if (i == 0) row_ptr[NNODES] = NEDGES + NNODES;
}

// atomic-free scatter using precomputed ranks (rank 0 = self-loop)
__global__ void k_scatter(const int* __restrict__ ei,
                          const int* __restrict__ row_ptr,
                          const int* __restrict__ rank, int* __restrict__ csr) {
  int e = blockIdx.x * 256 + threadIdx.x;
  if (e < NEDGES) {
    int d = ei[NEDGES + e];
    csr[row_ptr[d] + 1 + rank[e]] = ei[e];
  }
}

// ---------------- MFMA GEMM body ----------------
// H[row,:] = X[row,:] @ W (128x128). X fp32 -> bf16 staged; Wt is bf16 [n][k].
// Writes packed-bf16 Hb and fused alpha_src / alpha_dst.
__device__ __forceinline__ void gemm_body(int blk, const float* __restrict__ X,
                                          const unsigned* __restrict__ Wt,
                                          const float* __restrict__ a_sL,
                                          const float* __restrict__ a_dL,
                                          unsigned* __restrict__ Hb,
                                          float* __restrict__ as_,
                                          float* __restrict__ ad_) {
  __shared__ unsigned short Xs[64][136];
  __shared__ unsigned short Wsh[128][136];
  int t = threadIdx.x;
  int lane = t & 63;
  int w = t >> 6;
  int row0 = blk * 64;

  {  // stage X (fp32 -> bf16), 64 rows x 128 cols
    int r = t >> 2;
    int gr = row0 + r;
    const float* xp = X + (size_t)gr * 128;
#pragma unroll
    for (int i = 0; i < 8; ++i) {
      int c4 = ((t & 3) + 4 * i) * 4;
      float4 v = make_float4(0.f, 0.f, 0.f, 0.f);
      if (gr < NNODES) v = *(const float4*)(xp + c4);
      unsigned lo = (unsigned)f2bf(v.x) | ((unsigned)f2bf(v.y) << 16);
      unsigned hi = (unsigned)f2bf(v.z) | ((unsigned)f2bf(v.w) << 16);
      *(uint2*)&Xs[r][c4] = make_uint2(lo, hi);
    }
  }
  {  // stage Wt (already bf16 [n][k]) -> LDS
    int n = t >> 1;
    const uint4* wp = (const uint4*)(Wt + n * 64 + (t & 1) * 32);
    int kh = (t & 1) * 64;
#pragma unroll
    for (int i = 0; i < 8; ++i) {
      uint4 v = wp[i];
      *(uint4*)&Wsh[n][kh + i * 8] = v;
    }
  }
  __syncthreads();

  int n16 = lane & 15;
  int quad = lane >> 4;
  int m0 = w * 16;
  f32x4 acc[8];
#pragma unroll
  for (int nt = 0; nt < 8; ++nt) {
    f32x4 z = {0.f, 0.f, 0.f, 0.f};
    acc[nt] = z;
  }
#pragma unroll
  for (int kk = 0; kk < 4; ++kk) {
    bf16x8 af = *(const bf16x8*)&Xs[m0 + n16][kk * 32 + quad * 8];
#pragma unroll
    for (int nt = 0; nt < 8; ++nt) {
      bf16x8 bf = *(const bf16x8*)&Wsh[nt * 16 + n16][kk * 32 + quad * 8];
      acc[nt] =
          __builtin_amdgcn_mfma_f32_16x16x32_bf16(af, bf, acc[nt], 0, 0, 0);
    }
  }

  // epilogue: alpha dots + packed-bf16 H write
  float asv[8], adv[8];
#pragma unroll
  for (int nt = 0; nt < 8; ++nt) {
    asv[nt] = a_sL[nt * 16 + n16];
    adv[nt] = a_dL[nt * 16 + n16];
  }
#pragma unroll
  for (int r = 0; r < 4; ++r) {
    int row = row0 + m0 + quad * 4 + r;
    bool ok = (row < NNODES);
    float ps0 = 0.f, pd0 = 0.f, ps1 = 0.f, pd1 = 0.f;
#pragma unroll
    for (int nt = 0; nt < 4; ++nt) {
      ps0 += acc[nt][r] * asv[nt];
      pd0 += acc[nt][r] * adv[nt];
      ps1 += acc[nt + 4][r] * asv[nt + 4];
      pd1 += acc[nt + 4][r] * adv[nt + 4];
    }
#pragma unroll
    for (int off = 1; off < 16; off <<= 1) {
      ps0 += __shfl_xor(ps0, off, 64);
      pd0 += __shfl_xor(pd0, off, 64);
      ps1 += __shfl_xor(ps1, off, 64);
      pd1 += __shfl_xor(pd1, off, 64);
    }
    if (ok && n16 == 0) {
      as_[row * 2 + 0] = ps0;
      as_[row * 2 + 1] = ps1;
      ad_[row * 2 + 0] = pd0;
      ad_[row * 2 + 1] = pd1;
    }
    if (ok) {
#pragma unroll
      for (int nt = 0; nt < 4; ++nt) {
        unsigned pk = (unsigned)f2bf(acc[nt][r]) |
                      ((unsigned)f2bf(acc[nt + 4][r]) << 16);
        Hb[(size_t)row * 64 + nt * 16 + n16] = pk;
      }
    }
  }
}

__global__ __launch_bounds__(256) void k_gemm(const float* __restrict__ X,
                                              const unsigned* __restrict__ Wt,
                                              const float* __restrict__ a_sL,
                                              const float* __restrict__ a_dL,
                                              unsigned* __restrict__ Hb,
                                              float* __restrict__ as_,
                                              float* __restrict__ ad_) {
  gemm_body(blockIdx.x, X, Wt, a_sL, a_dL, Hb, as_, ad_);
}

// fused: layer-0 GEMM | edge histogram (+rank) | per-graph node count.
__global__ __launch_bounds__(256) void k_front(
    const float* __restrict__ X, const unsigned* __restrict__ Wt,
    const float* __restrict__ a_sL, const float* __restrict__ a_dL,
    unsigned* __restrict__ Hb, float* __restrict__ as_,
    float* __restrict__ ad_, const int* __restrict__ ei, int* __restrict__ deg,
    int* __restrict__ rank, const int* __restrict__ batch,
    float* __restrict__ gcnt) {
  int b = blockIdx.x;
  if (b < GEMMB) {
    gemm_body(b, X, Wt, a_sL, a_dL, Hb, as_, ad_);
  } else if (b < GEMMB + HISTB) {
    int e = (b - GEMMB) * 256 + threadIdx.x;
    if (e < NEDGES) rank[e] = atomicAdd(&deg[ei[NEDGES + e]], 1);
  } else {
    __shared__ float loc[NGRAPH];
    int t = threadIdx.x;
    if (t < NGRAPH) loc[t] = 0.f;
    __syncthreads();
    int n = (b - GEMMB - HISTB) * 256 + t;
    if (n < NNODES) atomicAdd(&loc[batch[n]], 1.f);
    __syncthreads();
    if (t < NGRAPH && loc[t] > 0.f) atomicAdd(&gcnt[t], loc[t]);
  }
}

// One wave per node: softmax (shift-invariant, no max pass) + aggregation.
__global__ __launch_bounds__(256) void k_aggregate(
    const unsigned* __restrict__ Hb, const float* __restrict__ as_,
    const float* __restrict__ ad_, const int* __restrict__ row_ptr,
    const int* __restrict__ csr, const float* __restrict__ bias,
    float* __restrict__ Xout) {
  __shared__ float2 wb[4][64];
  __shared__ int sb[4][64];
  int wv = threadIdx.x >> 6;
  int lane = threadIdx.x & 63;
  int node = blockIdx.x * 4 + wv;
  if (node >= NNODES) return;
  int rs = row_ptr[node], re = row_ptr[node + 1];
  float2 adv = *(const float2*)&ad_[node * 2];
  const unsigned* Hl = Hb + lane;

  float z0 = 0.f, z1 = 0.f, acc0 = 0.f, acc1 = 0.f;
  for (int base = rs; base < re; base += 64) {
    int j = base + lane;
    float p0 = 0.f, p1 = 0.f;
    int s = 0;
    if (j < re) {
      s = csr[j];
      float2 asv = *(const float2*)&as_[s * 2];
      float e0 = asv.x + adv.x; e0 = (e0 > 0.f) ? e0 : NEG_SLOPE * e0;
      float e1 = asv.y + adv.y; e1 = (e1 > 0.f) ? e1 : NEG_SLOPE * e1;
      p0 = __expf(e0);
      p1 = __expf(e1);
    }
    z0 += p0;
    z1 += p1;
    wb[wv][lane] = make_float2(p0, p1);
    sb[wv][lane] = s;
    WAVE_SYNC();
    int cl = min(64, re - base);
    int jj = 0;
    for (; jj + 8 <= cl; jj += 8) {
      unsigned v0 = Hl[(size_t)sb[wv][jj + 0] * 64];
      unsigned v1 = Hl[(size_t)sb[wv][jj + 1] * 64];
      unsigned v2 = Hl[(size_t)sb[wv][jj + 2] * 64];
      unsigned v3 = Hl[(size_t)sb[wv][jj + 3] * 64];
      unsigned v4 = Hl[(size_t)sb[wv][jj + 4] * 64];
      unsigned v5 = Hl[(size_t)sb[wv][jj + 5] * 64];
      unsigned v6 = Hl[(size_t)sb[wv][jj + 6] * 64];
      unsigned v7 = Hl[(size_t)sb[wv][jj + 7] * 64];
      float2 w0 = wb[wv][jj + 0], w1 = wb[wv][jj + 1];
      float2 w2 = wb[wv][jj + 2], w3 = wb[wv][jj + 3];
      float2 w4 = wb[wv][jj + 4], w5 = wb[wv][jj + 5];
      float2 w6 = wb[wv][jj + 6], w7 = wb[wv][jj + 7];
      acc0 += w0.x * bflo(v0); acc1 += w0.y * bfhi(v0);
      acc0 += w1.x * bflo(v1); acc1 += w1.y * bfhi(v1);
      acc0 += w2.x * bflo(v2); acc1 += w2.y * bfhi(v2);
      acc0 += w3.x * bflo(v3); acc1 += w3.y * bfhi(v3);
      acc0 += w4.x * bflo(v4); acc1 += w4.y * bfhi(v4);
      acc0 += w5.x * bflo(v5); acc1 += w5.y * bfhi(v5);
      acc0 += w6.x * bflo(v6); acc1 += w6.y * bfhi(v6);
      acc0 += w7.x * bflo(v7); acc1 += w7.y * bfhi(v7);
    }
    for (; jj < cl; ++jj) {
      unsigned v = Hl[(size_t)sb[wv][jj] * 64];
      float2 w = wb[wv][jj];
      acc0 += w.x * bflo(v);
      acc1 += w.y * bfhi(v);
    }
    WAVE_SYNC();
  }
#pragma unroll
  for (int off = 32; off > 0; off >>= 1) {
    z0 += __shfl_xor(z0, off, 64);
    z1 += __shfl_xor(z1, off, 64);
  }
  float o0 = acc0 / z0 + bias[lane];
  float o1 = acc1 / z1 + bias[64 + lane];
  o0 = (o0 > 0.f) ? o0 : expm1f(o0);  // ELU
  o1 = (o1 > 0.f) ? o1 : expm1f(o1);
  Xout[(size_t)node * 128 + lane] = o0;
  Xout[(size_t)node * 128 + 64 + lane] = o1;
}

// ---------------- pooling + classifier ----------------

__global__ __launch_bounds__(128) void k_pool(const float* __restrict__ Xf,
                                              const int* __restrict__ batch,
                                              float* __restrict__ gsum) {
  int c = threadIdx.x;
  int n0 = blockIdx.x * 64;
  if (n0 >= NNODES) return;
  int n1 = min(n0 + 64, NNODES);
  int cur = batch[n0];
  float acc = 0.f;
  for (int n = n0; n < n1; ++n) {
    int g = batch[n];
    if (g != cur) {
      atomicAdd(&gsum[cur * FDIM + c], acc);
      acc = 0.f;
      cur = g;
    }
    acc += Xf[(size_t)n * 128 + c];
  }
  atomicAdd(&gsum[cur * FDIM + c], acc);
}

__global__ __launch_bounds__(64) void k_final(const float* __restrict__ gsum,
                                              const float* __restrict__ gcnt,
                                              const float* __restrict__ lw,
                                              const float* __restrict__ lb,
                                              float* __restrict__ out) {
  int g = threadIdx.x;
  float inv = 1.f / fmaxf(gcnt[g], 1.f);
  float lg[NCLS];
#pragma unroll
  for (int k = 0; k < NCLS; ++k) lg[k] = lb[k];
  for (int c = 0; c < FDIM; ++c) {
    float pv = gsum[g * FDIM + c] * inv;
#pragma unroll
    for (int k = 0; k < NCLS; ++k) lg[k] += pv * lw[c * NCLS + k];
  }
  float mx = lg[0];
#pragma unroll
  for (int k = 1; k < NCLS; ++k) mx = fmaxf(mx, lg[k]);
  float s = 0.f;
#pragma unroll
  for (int k = 0; k < NCLS; ++k) {
    lg[k] = expf(lg[k] - mx);
    s += lg[k];
  }
  float invs = 1.f / s;
#pragma unroll
  for (int k = 0; k < NCLS; ++k) out[g * NCLS + k] = lg[k] * invs;
}

// ---------------- launch ----------------

extern "C" void kernel_launch(void* const* d_in, const int* in_sizes, int n_in,
                              void* d_out, int out_size, void* d_ws,
                              size_t ws_size, hipStream_t stream) {
  const float* x = (const float*)d_in[0];
  const int* ei = (const int*)d_in[1];
  const int* batch = (const int*)d_in[2];
  const float* W = (const float*)d_in[3];
  const float* a_s = (const float*)d_in[4];
  const float* a_d = (const float*)d_in[5];
  const float* bias = (const float*)d_in[6];
  const float* lw = (const float*)d_in[7];
  const float* lb = (const float*)d_in[8];
  float* out = (float*)d_out;

  unsigned* Hb = (unsigned*)d_ws;                  // N*64 packed bf16 pairs
  float* xb = (float*)(Hb + (size_t)NNODES * 64);  // N*128
  float* as_ = xb + (size_t)NNODES * 128;          // N*2
  float* ad_ = as_ + (size_t)NNODES * 2;           // N*2
  float* gsum = ad_ + (size_t)NNODES * 2;          // 64*128   } one memset
  float* gcnt = gsum + NGRAPH * FDIM;              // 64       }
  int* deg = (int*)(gcnt + NGRAPH);                // N        }
  int* row_ptr = deg + NNODES;                     // N+1
  int* csr = row_ptr + (NNODES + 1);               // E+N
  int* pre = csr + (NEDGES + NNODES);              // N
  int* bsum = pre + NNODES;                        // NBLK
  int* boff = bsum + NBLK;                         // NBLK
  int* rank = boff + NBLK;                         // E
  unsigned* Wt = (unsigned*)(rank + NEDGES);       // 3*8192 (bf16 W^T)

  hipMemsetAsync(gsum, 0, (NGRAPH * FDIM + NGRAPH + NNODES) * 4, stream);
  k_wprep<<<NLAYERS, 256, 0, stream>>>(W, Wt);
  // layer-0 GEMM overlapped with edge histogram + graph-size count
  k_front<<<GEMMB + HISTB + NBLK, 256, 0, stream>>>(
      x, Wt, a_s, a_d, Hb, as_, ad_, ei, deg, rank, batch, gcnt);
  k_scan1<<<NBLK, 256, 0, stream>>>(deg, pre, bsum);
  k_scan2<<<1, 256, 0, stream>>>(bsum, boff);
  k_scan3<<<NBLK, 256, 0, stream>>>(pre, boff, row_ptr, csr);
  k_scatter<<<HISTB, 256, 0, stream>>>(ei, row_ptr, rank, csr);

  for (int l = 0; l < NLAYERS; ++l) {
    if (l > 0) {
      k_gemm<<<GEMMB, 256, 0, stream>>>(xb, Wt + (size_t)l * FDIM * FDIM / 2,
                                        a_s + l * FDIM, a_d + l * FDIM, Hb,
                                        as_, ad_);
    }
    k_aggregate<<<(NNODES + 3) / 4, 256, 0, stream>>>(
        Hb, as_, ad_, row_ptr, csr, bias + l * FDIM, xb);
  }
  k_pool<<<(NNODES + 63) / 64, 128, 0, stream>>>(xb, batch, gsum);
  k_final<<<1, 64, 0, stream>>>(gsum, gcnt, lw, lb, out);
}

// Round 5
// 323.071 us; speedup vs baseline: 2.1354x; 1.0357x over previous
//
#include <hip/hip_runtime.h>
#include <math.h>

#define NNODES 50000
#define NEDGES 800000
#define NLAYERS 3
#define NHEADS 2
#define NCH 64
#define FDIM 128   // == NHEADS*NCH
#define NCLS 10
#define NGRAPH 64
#define NEG_SLOPE 0.2f
#define NBLK ((NNODES + 255) / 256)   // 196
#define GEMMB ((NNODES + 63) / 64)    // 782
#define NB 391                        // buckets = ceil(50000/128)
#define RADB 391                      // radix blocks = ceil(800000/2048)
#define SCN (NB * RADB)               // 152881
#define NS1 ((SCN + 511) / 512)       // 299

#define WAVE_SYNC()                      \
  do {                                   \
    __builtin_amdgcn_wave_barrier();     \
    __asm__ volatile("" ::: "memory");   \
  } while (0)

typedef __attribute__((ext_vector_type(8))) short bf16x8;
typedef __attribute__((ext_vector_type(4))) float f32x4;

__device__ __forceinline__ unsigned short f2bf(float f) {
  unsigned int u = __builtin_bit_cast(unsigned int, f);
  unsigned int r = u + 0x7FFFu + ((u >> 16) & 1u);  // RNE
  return (unsigned short)(r >> 16);
}
__device__ __forceinline__ float bflo(unsigned v) {
  return __builtin_bit_cast(float, v << 16);
}
__device__ __forceinline__ float bfhi(unsigned v) {
  return __builtin_bit_cast(float, v & 0xFFFF0000u);
}

// ---------------- W prep: transpose + bf16 (3 blocks, one per layer) -------
__global__ __launch_bounds__(256) void k_wprep(const float* __restrict__ W,
                                               unsigned* __restrict__ Wt) {
  __shared__ float Lt[128][132];
  int l = blockIdx.x;
  const float* Wl = W + (size_t)l * FDIM * FDIM;
  unsigned* Wtl = Wt + (size_t)l * FDIM * FDIM / 2;
  int t = threadIdx.x;
#pragma unroll
  for (int i = 0; i < 16; ++i) {
    int k = (t >> 5) + 8 * i;
    int n4 = (t & 31) * 4;
    float4 v = *(const float4*)(Wl + (size_t)k * 128 + n4);
    Lt[k][n4 + 0] = v.x;
    Lt[k][n4 + 1] = v.y;
    Lt[k][n4 + 2] = v.z;
    Lt[k][n4 + 3] = v.w;
  }
  __syncthreads();
  int n = t >> 1;
  int kh = (t & 1) * 64;
  for (int kk = 0; kk < 64; kk += 2) {
    unsigned pk = (unsigned)f2bf(Lt[kh + kk][n]) |
                  ((unsigned)f2bf(Lt[kh + kk + 1][n]) << 16);
    Wtl[n * 64 + (kh >> 1) + (kk >> 1)] = pk;
  }
}

// ---------------- MFMA GEMM body (no LDS) ----------------
// H[row,:] = X[row,:] @ W. A-frags from X directly (fp32->bf16), B-frags from
// Wt[n][k] (bf16) directly. Writes packed-bf16 Hb and fused alphas.
__device__ __forceinline__ void gemm_body(int blk, const float* __restrict__ X,
                                          const unsigned* __restrict__ Wt,
                                          const float* __restrict__ a_sL,
                                          const float* __restrict__ a_dL,
                                          unsigned* __restrict__ Hb,
                                          float* __restrict__ as_,
                                          float* __restrict__ ad_) {
  int t = threadIdx.x;
  int lane = t & 63;
  int w = t >> 6;
  int row0 = blk * 64;
  int n16 = lane & 15;
  int quad = lane >> 4;
  int m0 = w * 16;

  int gr = row0 + m0 + n16;
  const float* xp = X + (size_t)min(gr, NNODES - 1) * 128;

  f32x4 acc[8];
#pragma unroll
  for (int nt = 0; nt < 8; ++nt) {
    f32x4 z = {0.f, 0.f, 0.f, 0.f};
    acc[nt] = z;
  }
#pragma unroll
  for (int kk = 0; kk < 4; ++kk) {
    float4 va = *(const float4*)(xp + kk * 32 + quad * 8);
    float4 vb = *(const float4*)(xp + kk * 32 + quad * 8 + 4);
    bf16x8 af;
    af[0] = (short)f2bf(va.x); af[1] = (short)f2bf(va.y);
    af[2] = (short)f2bf(va.z); af[3] = (short)f2bf(va.w);
    af[4] = (short)f2bf(vb.x); af[5] = (short)f2bf(vb.y);
    af[6] = (short)f2bf(vb.z); af[7] = (short)f2bf(vb.w);
#pragma unroll
    for (int nt = 0; nt < 8; ++nt) {
      // B row n = nt*16+n16, dwords kk*16 + quad*4 .. +4
      bf16x8 bf = *(const bf16x8*)(Wt + (size_t)(nt * 16 + n16) * 64 +
                                   kk * 16 + quad * 4);
      acc[nt] =
          __builtin_amdgcn_mfma_f32_16x16x32_bf16(af, bf, acc[nt], 0, 0, 0);
    }
  }

  // epilogue: alpha dots + packed-bf16 H write
  float asv[8], adv[8];
#pragma unroll
  for (int nt = 0; nt < 8; ++nt) {
    asv[nt] = a_sL[nt * 16 + n16];
    adv[nt] = a_dL[nt * 16 + n16];
  }
#pragma unroll
  for (int r = 0; r < 4; ++r) {
    int row = row0 + m0 + quad * 4 + r;
    bool ok = (row < NNODES);
    float ps0 = 0.f, pd0 = 0.f, ps1 = 0.f, pd1 = 0.f;
#pragma unroll
    for (int nt = 0; nt < 4; ++nt) {
      ps0 += acc[nt][r] * asv[nt];
      pd0 += acc[nt][r] * adv[nt];
      ps1 += acc[nt + 4][r] * asv[nt + 4];
      pd1 += acc[nt + 4][r] * adv[nt + 4];
    }
#pragma unroll
    for (int off = 1; off < 16; off <<= 1) {
      ps0 += __shfl_xor(ps0, off, 64);
      pd0 += __shfl_xor(pd0, off, 64);
      ps1 += __shfl_xor(ps1, off, 64);
      pd1 += __shfl_xor(pd1, off, 64);
    }
    if (ok && n16 == 0) {
      as_[row * 2 + 0] = ps0;
      as_[row * 2 + 1] = ps1;
      ad_[row * 2 + 0] = pd0;
      ad_[row * 2 + 1] = pd1;
    }
    if (ok) {
#pragma unroll
      for (int nt = 0; nt < 4; ++nt) {
        unsigned pk = (unsigned)f2bf(acc[nt][r]) |
                      ((unsigned)f2bf(acc[nt + 4][r]) << 16);
        Hb[(size_t)row * 64 + nt * 16 + n16] = pk;
      }
    }
  }
}

__global__ __launch_bounds__(256) void k_gemm(const float* __restrict__ X,
                                              const unsigned* __restrict__ Wt,
                                              const float* __restrict__ a_sL,
                                              const float* __restrict__ a_dL,
                                              unsigned* __restrict__ Hb,
                                              float* __restrict__ as_,
                                              float* __restrict__ ad_) {
  gemm_body(blockIdx.x, X, Wt, a_sL, a_dL, Hb, as_, ad_);
}

// fused: layer-0 GEMM | radix pass A (bucket histogram) | per-graph count.
__global__ __launch_bounds__(256) void k_front(
    const float* __restrict__ X, const unsigned* __restrict__ Wt,
    const float* __restrict__ a_sL, const float* __restrict__ a_dL,
    unsigned* __restrict__ Hb, float* __restrict__ as_,
    float* __restrict__ ad_, const int* __restrict__ ei, int* __restrict__ bh,
    const int* __restrict__ batch, float* __restrict__ gcnt) {
  int b = blockIdx.x;
  if (b < GEMMB) {
    gemm_body(b, X, Wt, a_sL, a_dL, Hb, as_, ad_);
  } else if (b < GEMMB + RADB) {
    __shared__ int hist[NB];
    int blk = b - GEMMB;
    int t = threadIdx.x;
    for (int i = t; i < NB; i += 256) hist[i] = 0;
    __syncthreads();
    int e0 = blk * 2048;
#pragma unroll
    for (int i = 0; i < 8; ++i) {
      int e = e0 + i * 256 + t;
      if (e < NEDGES) atomicAdd(&hist[ei[NEDGES + e] >> 7], 1);
    }
    __syncthreads();
    for (int i = t; i < NB; i += 256) bh[i * RADB + blk] = hist[i];
  } else {
    __shared__ float loc[NGRAPH];
    int t = threadIdx.x;
    if (t < NGRAPH) loc[t] = 0.f;
    __syncthreads();
    int n = (b - GEMMB - RADB) * 256 + t;
    if (n < NNODES) atomicAdd(&loc[batch[n]], 1.f);
    __syncthreads();
    if (t < NGRAPH && loc[t] > 0.f) atomicAdd(&gcnt[t], loc[t]);
  }
}

// ---------------- scan of bh (col-major [bucket][block]) ----------------
__global__ __launch_bounds__(256) void k_s1(int* __restrict__ sc,
                                            int* __restrict__ bpart) {
  __shared__ int ps[256];
  int t = threadIdx.x;
  int f0 = blockIdx.x * 512 + 2 * t;
  int x0 = (f0 < SCN) ? sc[f0] : 0;
  int x1 = (f0 + 1 < SCN) ? sc[f0 + 1] : 0;
  int pair = x0 + x1;
  ps[t] = pair;
  __syncthreads();
  for (int off = 1; off < 256; off <<= 1) {
    int v = (t >= off) ? ps[t - off] : 0;
    __syncthreads();
    ps[t] += v;
    __syncthreads();
  }
  int ex = ps[t] - pair;
  if (f0 < SCN) sc[f0] = ex;
  if (f0 + 1 < SCN) sc[f0 + 1] = ex + x0;
  if (t == 255) bpart[blockIdx.x] = ps[255];
}

__global__ __launch_bounds__(256) void k_s2(int* __restrict__ bpart) {
  __shared__ int ps[256];
  int t = threadIdx.x;
  int x0 = (2 * t < NS1) ? bpart[2 * t] : 0;
  int x1 = (2 * t + 1 < NS1) ? bpart[2 * t + 1] : 0;
  int pair = x0 + x1;
  ps[t] = pair;
  __syncthreads();
  for (int off = 1; off < 256; off <<= 1) {
    int v = (t >= off) ? ps[t - off] : 0;
    __syncthreads();
    ps[t] += v;
    __syncthreads();
  }
  int ex = ps[t] - pair;
  if (2 * t < NS1) bpart[2 * t] = ex;
  if (2 * t + 1 < NS1) bpart[2 * t + 1] = ex + x0;
}

__global__ __launch_bounds__(256) void k_s3(int* __restrict__ sc,
                                            const int* __restrict__ bpart) {
  int t = threadIdx.x;
  int f0 = blockIdx.x * 512 + 2 * t;
  int add = bpart[blockIdx.x];
  if (f0 < SCN) sc[f0] += add;
  if (f0 + 1 < SCN) sc[f0 + 1] += add;
}

// ---------------- radix pass B: scatter edges into bucket regions ---------
__global__ __launch_bounds__(256) void k_passB(const int* __restrict__ ei,
                                               const int* __restrict__ sc,
                                               unsigned* __restrict__ ebuf) {
  __shared__ int curs[NB];
  int blk = blockIdx.x, t = threadIdx.x;
  for (int i = t; i < NB; i += 256) curs[i] = sc[i * RADB + blk];
  __syncthreads();
  int e0 = blk * 2048;
#pragma unroll
  for (int i = 0; i < 8; ++i) {
    int e = e0 + i * 256 + t;
    if (e < NEDGES) {
      int s = ei[e];
      int d = ei[NEDGES + e];
      int pos = atomicAdd(&curs[d >> 7], 1);
      ebuf[pos] = ((unsigned)s << 7) | (unsigned)(d & 127);
    }
  }
}

// ---------------- radix pass C: per-bucket CSR finalize ----------------
__global__ __launch_bounds__(256) void k_passC(const unsigned* __restrict__ ebuf,
                                               const int* __restrict__ sc,
                                               int* __restrict__ row_ptr,
                                               int* __restrict__ csr) {
  __shared__ int deg[128];
  __shared__ int scn[128];
  int b = blockIdx.x, t = threadIdx.x;
  int node0 = b * 128;
  int nn = min(128, NNODES - node0);
  int estart = sc[b * RADB];
  int eend = (b + 1 < NB) ? sc[(b + 1) * RADB] : NEDGES;
  if (t < 128) deg[t] = 0;
  __syncthreads();
  for (int e = estart + t; e < eend; e += 256)
    atomicAdd(&deg[ebuf[e] & 127], 1);
  __syncthreads();
  if (t < 128) scn[t] = (t < nn) ? deg[t] + 1 : 0;
  __syncthreads();
  for (int off = 1; off < 128; off <<= 1) {
    int v = (t < 128 && t >= off) ? scn[t - off] : 0;
    __syncthreads();
    if (t < 128) scn[t] += v;
    __syncthreads();
  }
  int base = estart + node0;
  if (t < nn) {
    int st = base + (t ? scn[t - 1] : 0);
    row_ptr[node0 + t] = st;
    csr[st] = node0 + t;  // self-loop at rank 0
    deg[t] = st + 1;      // reuse as cursor
  }
  if (b == 0 && t == 0) row_ptr[NNODES] = NEDGES + NNODES;
  __syncthreads();
  for (int e = estart + t; e < eend; e += 256) {
    unsigned v = ebuf[e];
    int pos = atomicAdd(&deg[v & 127], 1);
    csr[pos] = (int)(v >> 7);
  }
}

// One wave per node: softmax (shift-invariant) + aggregation.
__global__ __launch_bounds__(256) void k_aggregate(
    const unsigned* __restrict__ Hb, const float* __restrict__ as_,
    const float* __restrict__ ad_, const int* __restrict__ row_ptr,
    const int* __restrict__ csr, const float* __restrict__ bias,
    float* __restrict__ Xout) {
  __shared__ float2 wb[4][64];
  __shared__ int sb[4][64];
  int wv = threadIdx.x >> 6;
  int lane = threadIdx.x & 63;
  int node = blockIdx.x * 4 + wv;
  if (node >= NNODES) return;
  int rs = row_ptr[node], re = row_ptr[node + 1];
  float2 adv = *(const float2*)&ad_[node * 2];
  const unsigned* Hl = Hb + lane;

  float z0 = 0.f, z1 = 0.f, acc0 = 0.f, acc1 = 0.f;
  for (int base = rs; base < re; base += 64) {
    int j = base + lane;
    float p0 = 0.f, p1 = 0.f;
    int s = 0;
    if (j < re) {
      s = csr[j];
      float2 asv = *(const float2*)&as_[s * 2];
      float e0 = asv.x + adv.x; e0 = (e0 > 0.f) ? e0 : NEG_SLOPE * e0;
      float e1 = asv.y + adv.y; e1 = (e1 > 0.f) ? e1 : NEG_SLOPE * e1;
      p0 = __expf(e0);
      p1 = __expf(e1);
    }
    z0 += p0;
    z1 += p1;
    wb[wv][lane] = make_float2(p0, p1);
    sb[wv][lane] = s;
    WAVE_SYNC();
    int cl = min(64, re - base);
    int jj = 0;
    for (; jj + 8 <= cl; jj += 8) {
      unsigned v0 = Hl[(size_t)sb[wv][jj + 0] * 64];
      unsigned v1 = Hl[(size_t)sb[wv][jj + 1] * 64];
      unsigned v2 = Hl[(size_t)sb[wv][jj + 2] * 64];
      unsigned v3 = Hl[(size_t)sb[wv][jj + 3] * 64];
      unsigned v4 = Hl[(size_t)sb[wv][jj + 4] * 64];
      unsigned v5 = Hl[(size_t)sb[wv][jj + 5] * 64];
      unsigned v6 = Hl[(size_t)sb[wv][jj + 6] * 64];
      unsigned v7 = Hl[(size_t)sb[wv][jj + 7] * 64];
      float2 w0 = wb[wv][jj + 0], w1 = wb[wv][jj + 1];
      float2 w2 = wb[wv][jj + 2], w3 = wb[wv][jj + 3];
      float2 w4 = wb[wv][jj + 4], w5 = wb[wv][jj + 5];
      float2 w6 = wb[wv][jj + 6], w7 = wb[wv][jj + 7];
      acc0 += w0.x * bflo(v0); acc1 += w0.y * bfhi(v0);
      acc0 += w1.x * bflo(v1); acc1 += w1.y * bfhi(v1);
      acc0 += w2.x * bflo(v2); acc1 += w2.y * bfhi(v2);
      acc0 += w3.x * bflo(v3); acc1 += w3.y * bfhi(v3);
      acc0 += w4.x * bflo(v4); acc1 += w4.y * bfhi(v4);
      acc0 += w5.x * bflo(v5); acc1 += w5.y * bfhi(v5);
      acc0 += w6.x * bflo(v6); acc1 += w6.y * bfhi(v6);
      acc0 += w7.x * bflo(v7); acc1 += w7.y * bfhi(v7);
    }
    for (; jj < cl; ++jj) {
      unsigned v = Hl[(size_t)sb[wv][jj] * 64];
      float2 w = wb[wv][jj];
      acc0 += w.x * bflo(v);
      acc1 += w.y * bfhi(v);
    }
    WAVE_SYNC();
  }
#pragma unroll
  for (int off = 32; off > 0; off >>= 1) {
    z0 += __shfl_xor(z0, off, 64);
    z1 += __shfl_xor(z1, off, 64);
  }
  float o0 = acc0 / z0 + bias[lane];
  float o1 = acc1 / z1 + bias[64 + lane];
  o0 = (o0 > 0.f) ? o0 : expm1f(o0);  // ELU
  o1 = (o1 > 0.f) ? o1 : expm1f(o1);
  Xout[(size_t)node * 128 + lane] = o0;
  Xout[(size_t)node * 128 + 64 + lane] = o1;
}

// ---------------- pooling + classifier ----------------

__global__ __launch_bounds__(128) void k_pool(const float* __restrict__ Xf,
                                              const int* __restrict__ batch,
                                              float* __restrict__ gsum) {
  int c = threadIdx.x;
  int n0 = blockIdx.x * 64;
  if (n0 >= NNODES) return;
  int n1 = min(n0 + 64, NNODES);
  int cur = batch[n0];
  float acc = 0.f;
  for (int n = n0; n < n1; ++n) {
    int g = batch[n];
    if (g != cur) {
      atomicAdd(&gsum[cur * FDIM + c], acc);
      acc = 0.f;
      cur = g;
    }
    acc += Xf[(size_t)n * 128 + c];
  }
  atomicAdd(&gsum[cur * FDIM + c], acc);
}

__global__ __launch_bounds__(64) void k_final(const float* __restrict__ gsum,
                                              const float* __restrict__ gcnt,
                                              const float* __restrict__ lw,
                                              const float* __restrict__ lb,
                                              float* __restrict__ out) {
  int g = threadIdx.x;
  float inv = 1.f / fmaxf(gcnt[g], 1.f);
  float lg[NCLS];
#pragma unroll
  for (int k = 0; k < NCLS; ++k) lg[k] = lb[k];
  for (int c = 0; c < FDIM; ++c) {
    float pv = gsum[g * FDIM + c] * inv;
#pragma unroll
    for (int k = 0; k < NCLS; ++k) lg[k] += pv * lw[c * NCLS + k];
  }
  float mx = lg[0];
#pragma unroll
  for (int k = 1; k < NCLS; ++k) mx = fmaxf(mx, lg[k]);
  float s = 0.f;
#pragma unroll
  for (int k = 0; k < NCLS; ++k) {
    lg[k] = expf(lg[k] - mx);
    s += lg[k];
  }
  float invs = 1.f / s;
#pragma unroll
  for (int k = 0; k < NCLS; ++k) out[g * NCLS + k] = lg[k] * invs;
}

// ---------------- launch ----------------

extern "C" void kernel_launch(void* const* d_in, const int* in_sizes, int n_in,
                              void* d_out, int out_size, void* d_ws,
                              size_t ws_size, hipStream_t stream) {
  const float* x = (const float*)d_in[0];
  const int* ei = (const int*)d_in[1];
  const int* batch = (const int*)d_in[2];
  const float* W = (const float*)d_in[3];
  const float* a_s = (const float*)d_in[4];
  const float* a_d = (const float*)d_in[5];
  const float* bias = (const float*)d_in[6];
  const float* lw = (const float*)d_in[7];
  const float* lb = (const float*)d_in[8];
  float* out = (float*)d_out;

  unsigned* Hb = (unsigned*)d_ws;                  // N*64 packed bf16 pairs
  float* xb = (float*)(Hb + (size_t)NNODES * 64);  // N*128
  float* as_ = xb + (size_t)NNODES * 128;          // N*2
  float* ad_ = as_ + (size_t)NNODES * 2;           // N*2
  float* gsum = ad_ + (size_t)NNODES * 2;          // 64*128  } one memset
  float* gcnt = gsum + NGRAPH * FDIM;              // 64      }
  int* row_ptr = (int*)(gcnt + NGRAPH);            // N+1
  int* csr = row_ptr + (NNODES + 1);               // E+N
  int* sc = csr + (NEDGES + NNODES);               // NB*RADB
  int* bpart = sc + SCN;                           // NS1
  unsigned* ebuf = (unsigned*)(bpart + NS1);       // E (+pad)
  unsigned* Wt = ebuf + (NEDGES + 1024);           // 3*8192 (bf16 W^T)

  hipMemsetAsync(gsum, 0, (NGRAPH * FDIM + NGRAPH) * 4, stream);
  k_wprep<<<NLAYERS, 256, 0, stream>>>(W, Wt);
  // layer-0 GEMM overlapped with radix pass A + graph-size count
  k_front<<<GEMMB + RADB + NBLK, 256, 0, stream>>>(
      x, Wt, a_s, a_d, Hb, as_, ad_, ei, sc, batch, gcnt);
  k_s1<<<NS1, 256, 0, stream>>>(sc, bpart);
  k_s2<<<1, 256, 0, stream>>>(bpart);
  k_s3<<<NS1, 256, 0, stream>>>(sc, bpart);
  k_passB<<<RADB, 256, 0, stream>>>(ei, sc, ebuf);
  k_passC<<<NB, 256, 0, stream>>>(ebuf, sc, row_ptr, csr);

  for (int l = 0; l < NLAYERS; ++l) {
    if (l > 0) {
      k_gemm<<<GEMMB, 256, 0, stream>>>(xb, Wt + (size_t)l * FDIM * FDIM / 2,
                                        a_s + l * FDIM, a_d + l * FDIM, Hb,
                                        as_, ad_);
    }
    k_aggregate<<<(NNODES + 3) / 4, 256, 0, stream>>>(
        Hb, as_, ad_, row_ptr, csr, bias + l * FDIM, xb);
  }
  k_pool<<<(NNODES + 63) / 64, 128, 0, stream>>>(xb, batch, gsum);
  k_final<<<1, 64, 0, stream>>>(gsum, gcnt, lw, lb, out);
}